// Round 1
// baseline (1403.397 us; speedup 1.0000x reference)
//
#include <hip/hip_runtime.h>
#include <hip/hip_bf16.h>

// Problem constants from setup_inputs(): x (32,256,256,128) fp32 NHWC,
// entropy_weights (128,), pooling_bias (128,). Pool = stride = (2,2).
// Output: (32,128,128,128) fp32.
//
// Math: per window {x0..x3} (per channel):
//   m = max(xi); ei = exp(xi - m); s = Σ ei; p_i = ei/s
//   entropy = -Σ p_i log(p_i + 1e-6)
//           ≈ log(s) - (Σ ei (xi - m)) / s      (|err| ≤ ~4e-6 abs, << thr)
//   out = entropy * w[c] + b[c]

#define B_  32
#define H_  256
#define W_  256
#define C_  128

__global__ __launch_bounds__(256) void entropy_pool_kernel(
    const float4* __restrict__ x,     // as float4, C/4 = 32 per pixel
    const float*  __restrict__ w,
    const float*  __restrict__ bias,
    float4* __restrict__ out)
{
    // One thread per 4 output channels.
    // t layout: c4 (5 bits) | wo (7 bits) | ho (7 bits) | b
    const unsigned t  = blockIdx.x * blockDim.x + threadIdx.x;
    const unsigned c4 = t & 31u;
    unsigned tmp      = t >> 5;
    const unsigned wo = tmp & 127u;
    tmp >>= 7;
    const unsigned ho = tmp & 127u;
    const unsigned b  = tmp >> 7;

    // Input offsets in float4 units. Pixel stride = C/4 = 32; row stride = W*C/4 = 8192.
    const unsigned base = ((b * H_ + 2u * ho) * W_ + 2u * wo) * (C_ / 4) + c4;
    const float4 v00 = x[base];
    const float4 v01 = x[base + (C_ / 4)];
    const float4 v10 = x[base + W_ * (C_ / 4)];
    const float4 v11 = x[base + W_ * (C_ / 4) + (C_ / 4)];

    // Per-channel affine params (128 floats each; L1-resident broadcast).
    const float4 wv = ((const float4*)w)[c4];
    const float4 bv = ((const float4*)bias)[c4];

    float4 r;
    #pragma unroll
    for (int j = 0; j < 4; ++j) {
        float a0, a1, a2, a3, wj, bj;
        switch (j) {
            case 0: a0=v00.x; a1=v01.x; a2=v10.x; a3=v11.x; wj=wv.x; bj=bv.x; break;
            case 1: a0=v00.y; a1=v01.y; a2=v10.y; a3=v11.y; wj=wv.y; bj=bv.y; break;
            case 2: a0=v00.z; a1=v01.z; a2=v10.z; a3=v11.z; wj=wv.z; bj=bv.z; break;
            default:a0=v00.w; a1=v01.w; a2=v10.w; a3=v11.w; wj=wv.w; bj=bv.w; break;
        }
        const float m  = fmaxf(fmaxf(a0, a1), fmaxf(a2, a3));
        const float d0 = a0 - m, d1 = a1 - m, d2 = a2 - m, d3 = a3 - m;
        const float e0 = __expf(d0), e1 = __expf(d1), e2 = __expf(d2), e3 = __expf(d3);
        const float s  = e0 + e1 + e2 + e3;
        const float ws = e0 * d0 + e1 * d1 + e2 * d2 + e3 * d3;
        const float entropy = __logf(s) - ws * __frcp_rn(s);
        const float o = entropy * wj + bj;
        switch (j) {
            case 0: r.x = o; break;
            case 1: r.y = o; break;
            case 2: r.z = o; break;
            default:r.w = o; break;
        }
    }
    out[t] = r;
}

extern "C" void kernel_launch(void* const* d_in, const int* in_sizes, int n_in,
                              void* d_out, int out_size, void* d_ws, size_t ws_size,
                              hipStream_t stream) {
    const float4* x   = (const float4*)d_in[0];
    const float*  w   = (const float*)d_in[1];
    const float*  bia = (const float*)d_in[2];
    float4* out       = (float4*)d_out;

    // out_size = 32*128*128*128 = 67,108,864 -> 16,777,216 float4 threads
    const int threads = 256;
    const int total4  = out_size / 4;
    const int blocks  = total4 / threads;  // 65536
    entropy_pool_kernel<<<blocks, threads, 0, stream>>>(x, w, bia, out);
}